// Round 19
// baseline (476.860 us; speedup 1.0000x reference)
//
#include <hip/hip_runtime.h>
#include <hip/hip_bf16.h>

#define N_TOK 4096
#define DIM   1024
#define NEXP  8
#define FDIM  4096

#define BM 128
#define BN 128
#define BK 32
#define TILE (BM * BK)   // elems per LDS tile buffer (8 KB)

typedef __attribute__((ext_vector_type(8))) short bf16x8;
typedef __attribute__((ext_vector_type(4))) float f32x4;

__device__ __forceinline__ unsigned short f2bf(float f) {
    unsigned u = __builtin_bit_cast(unsigned, f);
    u = (u + 0x7fffu + ((u >> 16) & 1u)) >> 16;
    return (unsigned short)u;
}

__device__ __forceinline__ float bf2f(unsigned short u) {
    return __builtin_bit_cast(float, (unsigned)u << 16);
}

// exact-GELU via branch-free erf approx (A&S 7.1.26, |err_erf| < 1.5e-7 abs)
__device__ __forceinline__ float gelu_f(float v) {
    float x = v * 0.70710678118654752f;
    float ax = fabsf(x);
    float t = __builtin_amdgcn_rcpf(1.0f + 0.3275911f * ax);
    float poly = t * (0.254829592f + t * (-0.284496736f + t * (1.421413741f +
                 t * (-1.453152027f + t * 1.061405429f))));
    float e = __expf(-x * x);
    float er = copysignf(1.0f - poly * e, x);
    return 0.5f * v * (1.0f + er);
}

// async global->LDS, 16B per lane. LDS dest is wave-uniform base + lane*16.
__device__ __forceinline__ void gld16(const unsigned short* g, unsigned short* l) {
    __builtin_amdgcn_global_load_lds(
        (const __attribute__((address_space(1))) unsigned int*)g,
        (__attribute__((address_space(3))) unsigned int*)l, 16, 0, 0);
}

// small (64x64) transpose tile body: fp32 [R][C] -> bf16 [C][R]; tl = [64][65] f32
__device__ __forceinline__ void tr_tile(const float* in, unsigned short* out,
                                        int R, int C, int r0, int c0, float (*tl)[65]) {
    int t = threadIdx.x;
    int lr = t >> 4, lc = (t & 15) * 4;
#pragma unroll
    for (int it = 0; it < 4; it++) {
        int r = lr + it * 16;
        float4 v = *(const float4*)(in + (size_t)(r0 + r) * C + c0 + lc);
        tl[lc + 0][r] = v.x; tl[lc + 1][r] = v.y; tl[lc + 2][r] = v.z; tl[lc + 3][r] = v.w;
    }
    __syncthreads();
    int orow = t >> 3, orr = (t & 7) * 8;
#pragma unroll
    for (int it = 0; it < 2; it++) {
        int oc = orow + it * 32;
        unsigned short o[8];
#pragma unroll
        for (int j = 0; j < 8; j++) o[j] = f2bf(tl[oc][orr + j]);
        *(int4*)(out + (size_t)(c0 + oc) * R + r0 + orr) = *(const int4*)o;
    }
}

// 128x128 transpose tile body (fp32 [R][C] -> bf16 [C][R]); tl = [128][132] ushort
__device__ __forceinline__ void tr_tile128(const float* in, unsigned short* out,
                                           int R, int C, int r0, int c0,
                                           unsigned short (*tl)[132], int t) {
    int lr = t >> 5, lcq = (t & 31) * 4;
#pragma unroll
    for (int it = 0; it < 16; it++) {
        int r = lr + it * 8;
        float4 v = *(const float4*)(in + (size_t)(r0 + r) * C + c0 + lcq);
        unsigned short o[4] = {f2bf(v.x), f2bf(v.y), f2bf(v.z), f2bf(v.w)};
        *(uint2*)&tl[r][lcq] = *(const uint2*)o;
    }
    __syncthreads();
    int rchunk = (t & 15) * 8;
#pragma unroll
    for (int it = 0; it < 8; it++) {
        int oc = (t >> 4) + it * 16;
        unsigned short o[8];
#pragma unroll
        for (int j = 0; j < 8; j++) o[j] = tl[rchunk + j][oc];
        *(int4*)(out + (size_t)(c0 + oc) * R + r0 + rchunk) = *(const int4*)o;
    }
}

// heterogeneous: blocks [0,2048) = W1 transpose (128x128 tiles);
// blocks [2048,3072) = router (4 waves/block; also writes xbf = bf16 copy of x).
__global__ __launch_bounds__(256) void tr1_router_kernel(
    const float* __restrict__ W1, unsigned short* __restrict__ w1t,
    const float* __restrict__ x, const float* __restrict__ Wr,
    unsigned short* __restrict__ xbf,
    int* __restrict__ tk_idx, float* __restrict__ tk_w, int* __restrict__ counts) {
    __shared__ __align__(16) unsigned short tl[128][132];
    int idx = blockIdx.x;
    int t = threadIdx.x;
    if (idx < 2048) {
        int e = idx >> 8, rem = idx & 255;
        int ct = rem & 31, rt8 = rem >> 5;
        tr_tile128(W1 + (size_t)e * DIM * FDIM, w1t + (size_t)e * DIM * FDIM,
                   DIM, FDIM, rt8 * 128, ct * 128, tl, t);
        return;
    }
    int n = (idx - 2048) * 4 + (t >> 6);
    int l = t & 63;
    float acc[8];
#pragma unroll
    for (int e = 0; e < 8; e++) acc[e] = 0.f;
    const float* xr = x + (size_t)n * DIM;
    unsigned short* xo = xbf + (size_t)n * DIM;
#pragma unroll 4
    for (int i = 0; i < 16; i++) {
        int d = i * 64 + l;
        float xv = xr[d];
        xo[d] = f2bf(xv);
        const float4* wr = (const float4*)(Wr + (size_t)d * 8);
        float4 w0 = wr[0], w1 = wr[1];
        acc[0] += xv * w0.x; acc[1] += xv * w0.y; acc[2] += xv * w0.z; acc[3] += xv * w0.w;
        acc[4] += xv * w1.x; acc[5] += xv * w1.y; acc[6] += xv * w1.z; acc[7] += xv * w1.w;
    }
#pragma unroll
    for (int off = 32; off >= 1; off >>= 1)
#pragma unroll
        for (int e = 0; e < 8; e++) acc[e] += __shfl_xor(acc[e], off);
    if (l == 0) {
        float mx = acc[0];
#pragma unroll
        for (int e = 1; e < 8; e++) mx = fmaxf(mx, acc[e]);
        float p[8], s = 0.f;
#pragma unroll
        for (int e = 0; e < 8; e++) { p[e] = expf(acc[e] - mx); s += p[e]; }
#pragma unroll
        for (int e = 0; e < 8; e++) p[e] /= s;
        int i0 = 0;
#pragma unroll
        for (int e = 1; e < 8; e++) if (p[e] > p[i0]) i0 = e;
        int i1 = (i0 == 0) ? 1 : 0;
#pragma unroll
        for (int e = 0; e < 8; e++) if (e != i0 && p[e] > p[i1]) i1 = e;
        float w0 = p[i0], w1 = p[i1], s2 = w0 + w1;
        w0 /= s2; w1 /= s2;
        tk_idx[2 * n] = i0; tk_idx[2 * n + 1] = i1;
        tk_w[2 * n] = w0;   tk_w[2 * n + 1] = w1;
        atomicAdd(&counts[i0], 1);
        atomicAdd(&counts[i1], 1);
    }
}

__global__ void scan_kernel(const int* __restrict__ counts, int* __restrict__ offs,
                            int* __restrict__ cursor) {
    if (threadIdx.x == 0 && blockIdx.x == 0) {
        int a = 0;
        for (int e = 0; e < NEXP; e++) { offs[e] = a; cursor[e] = a; a += counts[e]; }
        offs[NEXP] = a;
    }
}

__global__ void fill_kernel(const int* __restrict__ tk_idx, int* __restrict__ cursor,
                            int* __restrict__ perm, int* __restrict__ inv) {
    int n = blockIdx.x * blockDim.x + threadIdx.x;
    if (n >= N_TOK) return;
    int i0 = tk_idx[2 * n], i1 = tk_idx[2 * n + 1];
    int p0 = atomicAdd(&cursor[i0], 1);
    perm[p0] = 2 * n;
    inv[2 * n] = p0;
    int p1 = atomicAdd(&cursor[i1], 1);
    perm[p1] = 2 * n + 1;
    inv[2 * n + 1] = p1;
}

// ---------------- GEMM core: asymmetric ring (A depth-2/ring-3, B depth-1/ring-2) ----------------
// LDS: As 3x8KB + Bs 2x8KB = 40 KB -> 4 blocks/CU.
// ISSUE ORDER FIX (r18 NaN): B is issued BEFORE the deeper-prefetched A in every
// iteration, so the oldest loads in the vm queue are always a complete (A(t),B(t))
// pair and vmcnt(6) drains exactly that pair.
//   prologue: A0, B0, A1                               (6 loads)
//   iter t:   stageB(t+1); stageA(t+2); vmcnt(6)       queue [A(t),B(t),A(t+1),B(t+1),A(t+2)]
//             -> drains A(t),B(t); 6 remain | barrier | compute | barrier
//   tail:     stageB(NT-1); vmcnt(4) -> drains (NT-2) pair; then vmcnt(0) for last.
// B ring-2 reuse fenced by end-of-iteration barrier (writes issued after all reads).
// Swizzle: phys 16B-block = logical ^ ((row>>1)&3); inverse on per-lane GLOBAL src.

#define GEMM_CORE(K_, NT_, AROW_PTR_, B_)                                               \
    int t = threadIdx.x;                                                                \
    int lane = t & 63, wid = t >> 6;                                                    \
    int wm = wid >> 1, wn = wid & 1;                                                    \
    int arow_base = rt * BM;                                                            \
    int srow = lane >> 2;                                                               \
    int logb = (lane & 3) ^ ((lane >> 3) & 3);                                          \
    const unsigned short* gA[2];                                                        \
    const unsigned short* gB[2];                                                        \
    _Pragma("unroll")                                                                   \
    for (int j = 0; j < 2; j++) {                                                       \
        int ra = min(arow_base + wid * 32 + j * 16 + srow, cnt - 1);                    \
        gA[j] = (AROW_PTR_) + logb * 8;                                                 \
        gB[j] = B_ + (size_t)(n0 + wid * 32 + j * 16 + srow) * K_ + logb * 8;           \
    }                                                                                   \
    f32x4 acc[4][4];                                                                    \
    _Pragma("unroll")                                                                   \
    for (int i = 0; i < 4; i++)                                                         \
        _Pragma("unroll")                                                               \
        for (int j = 0; j < 4; j++) acc[i][j] = (f32x4){0.f, 0.f, 0.f, 0.f};            \
    int rl = lane & 15;                                                                 \
    int kq = lane >> 4;                                                                 \
    int pb8 = (kq ^ ((rl >> 1) & 3)) * 8;                                               \
    auto stageA = [&](int buf) {                                                        \
        unsigned short* la = As + buf * TILE + wid * 32 * BK;                           \
        _Pragma("unroll")                                                               \
        for (int j = 0; j < 2; j++) { gld16(gA[j], la + j * 16 * BK); gA[j] += BK; }    \
    };                                                                                  \
    auto stageB = [&](int buf) {                                                        \
        unsigned short* lb = Bs + buf * TILE + wid * 32 * BK;                           \
        _Pragma("unroll")                                                               \
        for (int j = 0; j < 2; j++) { gld16(gB[j], lb + j * 16 * BK); gB[j] += BK; }    \
    };                                                                                  \
    auto compute = [&](int bufA, int bufB) {                                            \
        const unsigned short* as = As + bufA * TILE;                                    \
        const unsigned short* bs = Bs + bufB * TILE;                                    \
        bf16x8 af[4], bfr[4];                                                           \
        _Pragma("unroll")                                                               \
        for (int mf = 0; mf < 4; mf++)                                                  \
            af[mf] = *(const bf16x8*)(as + (wm * 64 + mf * 16 + rl) * BK + pb8);        \
        _Pragma("unroll")                                                               \
        for (int nf = 0; nf < 4; nf++)                                                  \
            bfr[nf] = *(const bf16x8*)(bs + (wn * 64 + nf * 16 + rl) * BK + pb8);       \
        _Pragma("unroll")                                                               \
        for (int mf = 0; mf < 4; mf++)                                                  \
            _Pragma("unroll")                                                           \
            for (int nf = 0; nf < 4; nf++)                                              \
                acc[mf][nf] = __builtin_amdgcn_mfma_f32_16x16x32_bf16(                  \
                    af[mf], bfr[nf], acc[mf][nf], 0, 0, 0);                             \
    };                                                                                  \
    stageA(0); stageB(0); stageA(1);      /* queue: A0,B0,A1 */                         \
    int ca = 0;                                                                         \
    for (int it = 0; it < NT_ - 2; ++it) {                                              \
        int sa = ca + 2; if (sa >= 3) sa -= 3;                                          \
        stageB((it + 1) & 1);             /* B(it+1) FIRST */                           \
        stageA(sa);                       /* A(it+2) */                                 \
        asm volatile("s_waitcnt vmcnt(6)" ::: "memory"); /* drains A(it),B(it) */       \
        __builtin_amdgcn_s_barrier();                                                   \
        compute(ca, it & 1);                                                            \
        __builtin_amdgcn_s_barrier();     /* fences B ring-2 / A ring-3 reuse */        \
        ca = ca + 1; if (ca >= 3) ca -= 3;                                              \
    }                                                                                   \
    stageB((NT_ - 1) & 1);                /* B(NT-1); A(NT-1) already staged */         \
    asm volatile("s_waitcnt vmcnt(4)" ::: "memory"); /* drains (NT-2) pair */           \
    __builtin_amdgcn_s_barrier();                                                       \
    compute(ca, (NT_ - 2) & 1);                                                         \
    __builtin_amdgcn_s_barrier();                                                       \
    ca = ca + 1; if (ca >= 3) ca -= 3;                                                  \
    asm volatile("s_waitcnt vmcnt(0)" ::: "memory");                                    \
    __builtin_amdgcn_s_barrier();                                                       \
    compute(ca, (NT_ - 1) & 1);

// heterogeneous: 16-block groups, sub 0-7 = gemm1 tiles (b%8 XCD mapping),
// sub 8-15 = W2-transpose 64x64 tiles. A staged via perm indirection.
__global__ __launch_bounds__(256) void gemm1_tr2_kernel(
    const unsigned short* __restrict__ xbf, const unsigned short* __restrict__ w1t,
    unsigned short* __restrict__ h, const int* __restrict__ counts, const int* __restrict__ offs,
    const int* __restrict__ perm,
    const float* __restrict__ W2, unsigned short* __restrict__ w2t) {
    __shared__ __align__(16) char shraw[5 * TILE * sizeof(unsigned short)];  // 40 KB
    int Lx = blockIdx.x;
    int grp = Lx >> 4, sub = Lx & 15;
    if (sub >= 8) {
        int id = grp * 8 + (sub - 8);
        float (*tl)[65] = (float(*)[65])shraw;   // 16.9 KB of 40
        int e = id >> 10, rem = id & 1023;
        int cx = rem & 15, ry = rem >> 4;
        tr_tile(W2 + (size_t)e * DIM * FDIM, w2t + (size_t)e * DIM * FDIM,
                FDIM, DIM, ry * 64, cx * 64, tl);
        return;
    }
    unsigned short* As = (unsigned short*)shraw;
    unsigned short* Bs = As + 3 * TILE;
    int pos = sub * 1024 + grp;
    const int NTX = N_TOK / BM;
    const int NTY = FDIM / BN;
    int rt = pos % NTX;
    int tmp = pos / NTX;
    int n0 = (tmp % NTY) * BN;
    int e = tmp / NTY;
    int cnt = counts[e];
    if (rt * BM >= cnt) return;
    int off = offs[e];
    const unsigned short* Bp = w1t + (size_t)e * FDIM * DIM;

    GEMM_CORE(DIM, 32,
              (xbf + (size_t)(perm[off + ra] >> 1) * DIM),
              Bp)

    int rq = lane >> 4;
#pragma unroll
    for (int mf = 0; mf < 4; mf++) {
#pragma unroll
        for (int r = 0; r < 4; r++) {
            int row_local = wm * 64 + mf * 16 + rq * 4 + r;
            int grow = arow_base + row_local;
            if (grow < cnt) {
                unsigned short* hp = h + (size_t)(off + grow) * FDIM + n0 + wn * 64;
#pragma unroll
                for (int nf = 0; nf < 4; nf++)
                    hp[nf * 16 + rl] = f2bf(gelu_f(acc[mf][nf][r]));
            }
        }
    }
}

// GEMM2: ybuf = h @ w2t^T (K=4096 -> NT=128, N=1024); bf16 stores
__global__ __launch_bounds__(256) void gemm2_kernel(
    const unsigned short* __restrict__ h, const unsigned short* __restrict__ w2t,
    unsigned short* __restrict__ ybuf, const int* __restrict__ counts, const int* __restrict__ offs) {
    __shared__ unsigned short As[3 * TILE];
    __shared__ unsigned short Bs[2 * TILE];
    int L = blockIdx.x;
    int pos = (L & 7) * 256 + (L >> 3);
    int rt = pos & 31;
    int nt = (pos >> 5) & 7;
    int e = pos >> 8;
    int cnt = counts[e];
    if (rt * BM >= cnt) return;
    int off = offs[e];
    int n0 = nt * BN;
    const unsigned short* Bp = w2t + (size_t)e * DIM * FDIM;

    GEMM_CORE(FDIM, 128,
              (h + (size_t)(off + ra) * FDIM),
              Bp)

    int rq = lane >> 4;
#pragma unroll
    for (int mf = 0; mf < 4; mf++) {
#pragma unroll
        for (int r = 0; r < 4; r++) {
            int row_local = wm * 64 + mf * 16 + rq * 4 + r;
            int grow = arow_base + row_local;
            if (grow < cnt) {
                unsigned short* yp = ybuf + (size_t)(off + grow) * DIM + n0 + wn * 64;
#pragma unroll
                for (int nf = 0; nf < 4; nf++)
                    yp[nf * 16 + rl] = f2bf(acc[mf][nf][r]);
            }
        }
    }
}

// combine: out[n] = w0 * ybuf[inv[2n]] + w1 * ybuf[inv[2n+1]] (bf16 in, fp32 out);
// also writes aux_loss = 0
__global__ __launch_bounds__(256) void combine_kernel(
    const unsigned short* __restrict__ ybuf, const int* __restrict__ inv,
    const float* __restrict__ tk_w, float* __restrict__ out) {
    int n = blockIdx.x;
    int d = threadIdx.x * 4;
    int p0 = inv[2 * n], p1 = inv[2 * n + 1];
    float w0 = tk_w[2 * n], w1 = tk_w[2 * n + 1];
    ushort4 a = *(const ushort4*)(ybuf + (size_t)p0 * DIM + d);
    ushort4 b = *(const ushort4*)(ybuf + (size_t)p1 * DIM + d);
    float4 o = {w0 * bf2f(a.x) + w1 * bf2f(b.x),
                w0 * bf2f(a.y) + w1 * bf2f(b.y),
                w0 * bf2f(a.z) + w1 * bf2f(b.z),
                w0 * bf2f(a.w) + w1 * bf2f(b.w)};
    *(float4*)(out + (size_t)n * DIM + d) = o;
    if (n == 0 && threadIdx.x == 0) out[(size_t)N_TOK * DIM] = 0.f;  // aux_loss
}

extern "C" void kernel_launch(void* const* d_in, const int* in_sizes, int n_in,
                              void* d_out, int out_size, void* d_ws, size_t ws_size,
                              hipStream_t stream) {
    const float* x  = (const float*)d_in[0];
    const float* Wr = (const float*)d_in[1];
    const float* W1 = (const float*)d_in[2];
    const float* W2 = (const float*)d_in[3];
    float* out = (float*)d_out;

    char* w = (char*)d_ws;
    int*   counts = (int*)(w + 0);
    int*   offs   = (int*)(w + 64);
    int*   cursor = (int*)(w + 128);
    int*   tk_idx = (int*)(w + 256);
    float* tk_w   = (float*)(w + 256 + 32768);
    int*   perm   = (int*)(w + 256 + 65536);
    int*   inv    = (int*)(w + 256 + 131072);
    size_t base = (size_t)1 << 20;
    unsigned short* xbf  = (unsigned short*)(w + base);                       // 8 MB (bf16 x)
    unsigned short* hbuf = (unsigned short*)(w + base + ((size_t)16 << 20));  // 64 MB
    unsigned short* w1t  = (unsigned short*)(w + base + ((size_t)80 << 20));  // 64 MB (dead after gemm1)
    unsigned short* w2t  = (unsigned short*)(w + base + ((size_t)144 << 20)); // 64 MB
    unsigned short* ybuf = (unsigned short*)(w + base + ((size_t)80 << 20));  // 16 MB, aliases w1t

    hipMemsetAsync(w, 0, 256, stream);

    tr1_router_kernel<<<3072, 256, 0, stream>>>(W1, w1t, x, Wr, xbf, tk_idx, tk_w, counts);
    scan_kernel<<<1, 64, 0, stream>>>(counts, offs, cursor);
    fill_kernel<<<N_TOK / 256, 256, 0, stream>>>(tk_idx, cursor, perm, inv);

    gemm1_tr2_kernel<<<16384, 256, 0, stream>>>(xbf, w1t, hbuf, counts, offs, perm, W2, w2t);

    gemm2_kernel<<<32 * 8 * NEXP, 256, 0, stream>>>(hbuf, w2t, ybuf, counts, offs);
    combine_kernel<<<N_TOK, 256, 0, stream>>>(ybuf, inv, tk_w, out);
}

// Round 20
// 465.338 us; speedup vs baseline: 1.0248x; 1.0248x over previous
//
#include <hip/hip_runtime.h>
#include <hip/hip_bf16.h>

#define N_TOK 4096
#define DIM   1024
#define NEXP  8
#define FDIM  4096

#define BM 128
#define BN 128
#define BK 32
#define TILE (BM * BK)   // elems per LDS tile buffer (8 KB)

typedef __attribute__((ext_vector_type(8))) short bf16x8;
typedef __attribute__((ext_vector_type(4))) float f32x4;

__device__ __forceinline__ unsigned short f2bf(float f) {
    unsigned u = __builtin_bit_cast(unsigned, f);
    u = (u + 0x7fffu + ((u >> 16) & 1u)) >> 16;
    return (unsigned short)u;
}

__device__ __forceinline__ float bf2f(unsigned short u) {
    return __builtin_bit_cast(float, (unsigned)u << 16);
}

// exact-GELU via branch-free erf approx (A&S 7.1.26, |err_erf| < 1.5e-7 abs)
__device__ __forceinline__ float gelu_f(float v) {
    float x = v * 0.70710678118654752f;
    float ax = fabsf(x);
    float t = __builtin_amdgcn_rcpf(1.0f + 0.3275911f * ax);
    float poly = t * (0.254829592f + t * (-0.284496736f + t * (1.421413741f +
                 t * (-1.453152027f + t * 1.061405429f))));
    float e = __expf(-x * x);
    float er = copysignf(1.0f - poly * e, x);
    return 0.5f * v * (1.0f + er);
}

// async global->LDS, 16B per lane. LDS dest is wave-uniform base + lane*16.
__device__ __forceinline__ void gld16(const unsigned short* g, unsigned short* l) {
    __builtin_amdgcn_global_load_lds(
        (const __attribute__((address_space(1))) unsigned int*)g,
        (__attribute__((address_space(3))) unsigned int*)l, 16, 0, 0);
}

// small (64x64) transpose tile body: fp32 [R][C] -> bf16 [C][R]; tl = [64][65] f32
// (65 % 32 == 1 -> bank = c + r rotation, conflict-free scalar phases)
__device__ __forceinline__ void tr_tile(const float* in, unsigned short* out,
                                        int R, int C, int r0, int c0, float (*tl)[65]) {
    int t = threadIdx.x;
    int lr = t >> 4, lc = (t & 15) * 4;
#pragma unroll
    for (int it = 0; it < 4; it++) {
        int r = lr + it * 16;
        float4 v = *(const float4*)(in + (size_t)(r0 + r) * C + c0 + lc);
        tl[lc + 0][r] = v.x; tl[lc + 1][r] = v.y; tl[lc + 2][r] = v.z; tl[lc + 3][r] = v.w;
    }
    __syncthreads();
    int orow = t >> 3, orr = (t & 7) * 8;
#pragma unroll
    for (int it = 0; it < 2; it++) {
        int oc = orow + it * 32;
        unsigned short o[8];
#pragma unroll
        for (int j = 0; j < 8; j++) o[j] = f2bf(tl[oc][orr + j]);
        *(int4*)(out + (size_t)(c0 + oc) * R + r0 + orr) = *(const int4*)o;
    }
}

// 128x128 transpose tile body (fp32 [R][C] -> bf16 [C][R]); tl = [128][132] ushort
// (used only in the standalone tr1_router launch where it measured faster)
__device__ __forceinline__ void tr_tile128(const float* in, unsigned short* out,
                                           int R, int C, int r0, int c0,
                                           unsigned short (*tl)[132], int t) {
    int lr = t >> 5, lcq = (t & 31) * 4;
#pragma unroll
    for (int it = 0; it < 16; it++) {
        int r = lr + it * 8;
        float4 v = *(const float4*)(in + (size_t)(r0 + r) * C + c0 + lcq);
        unsigned short o[4] = {f2bf(v.x), f2bf(v.y), f2bf(v.z), f2bf(v.w)};
        *(uint2*)&tl[r][lcq] = *(const uint2*)o;
    }
    __syncthreads();
    int rchunk = (t & 15) * 8;
#pragma unroll
    for (int it = 0; it < 8; it++) {
        int oc = (t >> 4) + it * 16;
        unsigned short o[8];
#pragma unroll
        for (int j = 0; j < 8; j++) o[j] = tl[rchunk + j][oc];
        *(int4*)(out + (size_t)(c0 + oc) * R + r0 + rchunk) = *(const int4*)o;
    }
}

// heterogeneous: blocks [0,2048) = W1 transpose (128x128 tiles);
// blocks [2048,3072) = router (4 waves/block; also writes xbf = bf16 copy of x).
__global__ __launch_bounds__(256) void tr1_router_kernel(
    const float* __restrict__ W1, unsigned short* __restrict__ w1t,
    const float* __restrict__ x, const float* __restrict__ Wr,
    unsigned short* __restrict__ xbf,
    int* __restrict__ tk_idx, float* __restrict__ tk_w, int* __restrict__ counts) {
    __shared__ __align__(16) unsigned short tl[128][132];   // 33 KB
    int idx = blockIdx.x;
    int t = threadIdx.x;
    if (idx < 2048) {   // W1 [1024][4096] -> w1t [4096][1024]; 8 rt x 32 ct per expert
        int e = idx >> 8, rem = idx & 255;
        int ct = rem & 31, rt8 = rem >> 5;
        tr_tile128(W1 + (size_t)e * DIM * FDIM, w1t + (size_t)e * DIM * FDIM,
                   DIM, FDIM, rt8 * 128, ct * 128, tl, t);
        return;
    }
    // router: token n, one wave
    int n = (idx - 2048) * 4 + (t >> 6);
    int l = t & 63;
    float acc[8];
#pragma unroll
    for (int e = 0; e < 8; e++) acc[e] = 0.f;
    const float* xr = x + (size_t)n * DIM;
    unsigned short* xo = xbf + (size_t)n * DIM;
#pragma unroll 4
    for (int i = 0; i < 16; i++) {
        int d = i * 64 + l;
        float xv = xr[d];
        xo[d] = f2bf(xv);
        const float4* wr = (const float4*)(Wr + (size_t)d * 8);
        float4 w0 = wr[0], w1 = wr[1];
        acc[0] += xv * w0.x; acc[1] += xv * w0.y; acc[2] += xv * w0.z; acc[3] += xv * w0.w;
        acc[4] += xv * w1.x; acc[5] += xv * w1.y; acc[6] += xv * w1.z; acc[7] += xv * w1.w;
    }
#pragma unroll
    for (int off = 32; off >= 1; off >>= 1)
#pragma unroll
        for (int e = 0; e < 8; e++) acc[e] += __shfl_xor(acc[e], off);
    if (l == 0) {
        float mx = acc[0];
#pragma unroll
        for (int e = 1; e < 8; e++) mx = fmaxf(mx, acc[e]);
        float p[8], s = 0.f;
#pragma unroll
        for (int e = 0; e < 8; e++) { p[e] = expf(acc[e] - mx); s += p[e]; }
#pragma unroll
        for (int e = 0; e < 8; e++) p[e] /= s;
        int i0 = 0;
#pragma unroll
        for (int e = 1; e < 8; e++) if (p[e] > p[i0]) i0 = e;
        int i1 = (i0 == 0) ? 1 : 0;
#pragma unroll
        for (int e = 0; e < 8; e++) if (e != i0 && p[e] > p[i1]) i1 = e;
        float w0 = p[i0], w1 = p[i1], s2 = w0 + w1;
        w0 /= s2; w1 /= s2;
        tk_idx[2 * n] = i0; tk_idx[2 * n + 1] = i1;
        tk_w[2 * n] = w0;   tk_w[2 * n + 1] = w1;
        atomicAdd(&counts[i0], 1);
        atomicAdd(&counts[i1], 1);
    }
}

__global__ void scan_kernel(const int* __restrict__ counts, int* __restrict__ offs,
                            int* __restrict__ cursor) {
    if (threadIdx.x == 0 && blockIdx.x == 0) {
        int a = 0;
        for (int e = 0; e < NEXP; e++) { offs[e] = a; cursor[e] = a; a += counts[e]; }
        offs[NEXP] = a;
    }
}

__global__ void fill_kernel(const int* __restrict__ tk_idx, int* __restrict__ cursor,
                            int* __restrict__ perm, int* __restrict__ inv) {
    int n = blockIdx.x * blockDim.x + threadIdx.x;
    if (n >= N_TOK) return;
    int i0 = tk_idx[2 * n], i1 = tk_idx[2 * n + 1];
    int p0 = atomicAdd(&cursor[i0], 1);
    perm[p0] = 2 * n;
    inv[2 * n] = p0;
    int p1 = atomicAdd(&cursor[i1], 1);
    perm[p1] = 2 * n + 1;
    inv[2 * n + 1] = p1;
}

// ---------------- GEMM core (r5-exact, FROZEN): 3-buffer ring, 2-deep vmcnt(8), 2 barriers/iter ----------------
// Requires As/Bs (3*TILE ushorts each) in scope. 48 KB LDS -> 3 blocks/CU.
// Swizzle: phys 16B-block = logical_block ^ ((row>>1)&3); inverse on per-lane GLOBAL src, linear gld dest.
// AROW_PTR_: expression over `ra` yielding the A-row base pointer (enables permuted A).

#define GEMM_CORE(K_, NT_, AROW_PTR_, B_)                                               \
    int t = threadIdx.x;                                                                \
    int lane = t & 63, wid = t >> 6;                                                    \
    int wm = wid >> 1, wn = wid & 1;                                                    \
    int arow_base = rt * BM;                                                            \
    int srow = lane >> 2;                       /* row within 16-row segment */         \
    int logb = (lane & 3) ^ ((lane >> 3) & 3);  /* inverse-swizzled 16B block */        \
    const unsigned short* gA[2];                                                        \
    const unsigned short* gB[2];                                                        \
    _Pragma("unroll")                                                                   \
    for (int j = 0; j < 2; j++) {                                                       \
        int ra = min(arow_base + wid * 32 + j * 16 + srow, cnt - 1);                    \
        gA[j] = (AROW_PTR_) + logb * 8;                                                 \
        gB[j] = B_ + (size_t)(n0 + wid * 32 + j * 16 + srow) * K_ + logb * 8;           \
    }                                                                                   \
    f32x4 acc[4][4];                                                                    \
    _Pragma("unroll")                                                                   \
    for (int i = 0; i < 4; i++)                                                         \
        _Pragma("unroll")                                                               \
        for (int j = 0; j < 4; j++) acc[i][j] = (f32x4){0.f, 0.f, 0.f, 0.f};            \
    int rl = lane & 15;                                                                 \
    int kq = lane >> 4;                                                                 \
    int pb8 = (kq ^ ((rl >> 1) & 3)) * 8;       /* phys block offset for frag reads */  \
    auto stage = [&](int buf) {                                                         \
        unsigned short* la = As + buf * TILE + wid * 32 * BK;                           \
        unsigned short* lb = Bs + buf * TILE + wid * 32 * BK;                           \
        _Pragma("unroll")                                                               \
        for (int j = 0; j < 2; j++) { gld16(gA[j], la + j * 16 * BK); gA[j] += BK; }    \
        _Pragma("unroll")                                                               \
        for (int j = 0; j < 2; j++) { gld16(gB[j], lb + j * 16 * BK); gB[j] += BK; }    \
    };                                                                                  \
    auto compute = [&](int buf) {                                                       \
        const unsigned short* as = As + buf * TILE;                                     \
        const unsigned short* bs = Bs + buf * TILE;                                     \
        bf16x8 af[4], bfr[4];                                                           \
        _Pragma("unroll")                                                               \
        for (int mf = 0; mf < 4; mf++)                                                  \
            af[mf] = *(const bf16x8*)(as + (wm * 64 + mf * 16 + rl) * BK + pb8);        \
        _Pragma("unroll")                                                               \
        for (int nf = 0; nf < 4; nf++)                                                  \
            bfr[nf] = *(const bf16x8*)(bs + (wn * 64 + nf * 16 + rl) * BK + pb8);       \
        _Pragma("unroll")                                                               \
        for (int mf = 0; mf < 4; mf++)                                                  \
            _Pragma("unroll")                                                           \
            for (int nf = 0; nf < 4; nf++)                                              \
                acc[mf][nf] = __builtin_amdgcn_mfma_f32_16x16x32_bf16(                  \
                    af[mf], bfr[nf], acc[mf][nf], 0, 0, 0);                             \
    };                                                                                  \
    stage(0); stage(1);                                                                 \
    asm volatile("s_waitcnt vmcnt(4)" ::: "memory");  /* tile0 done, tile1 in flight */ \
    __builtin_amdgcn_s_barrier();                                                       \
    int cb = 0;                                                                         \
    for (int it = 0; it < NT_ - 2; ++it) {                                              \
        int sb = cb + 2; if (sb >= 3) sb -= 3;                                          \
        stage(sb);                                                                      \
        asm volatile("s_waitcnt vmcnt(8)" ::: "memory"); /* keep t+1,t+2 in flight */   \
        __builtin_amdgcn_s_barrier();                                                   \
        compute(cb);                                                                    \
        __builtin_amdgcn_s_barrier();                                                   \
        cb = cb + 1; if (cb >= 3) cb -= 3;                                              \
    }                                                                                   \
    asm volatile("s_waitcnt vmcnt(4)" ::: "memory");                                    \
    __builtin_amdgcn_s_barrier();                                                       \
    compute(cb);                                                                        \
    __builtin_amdgcn_s_barrier();                                                       \
    cb = cb + 1; if (cb >= 3) cb -= 3;                                                  \
    asm volatile("s_waitcnt vmcnt(0)" ::: "memory");                                    \
    __builtin_amdgcn_s_barrier();                                                       \
    compute(cb);

// heterogeneous: 16-block groups, sub 0-7 = gemm1 tiles (keeps b%8 XCD mapping),
// sub 8-15 = W2-transpose 64x64 tiles (conflict-free pattern).
// gemm1 A-rows staged DIRECTLY from xbf via perm (per-lane global addresses).
__global__ __launch_bounds__(256) void gemm1_tr2_kernel(
    const unsigned short* __restrict__ xbf, const unsigned short* __restrict__ w1t,
    unsigned short* __restrict__ h, const int* __restrict__ counts, const int* __restrict__ offs,
    const int* __restrict__ perm,
    const float* __restrict__ W2, unsigned short* __restrict__ w2t) {
    __shared__ __align__(16) char shraw[3 * TILE * 2 * sizeof(unsigned short)];  // 48 KB
    int Lx = blockIdx.x;
    int grp = Lx >> 4, sub = Lx & 15;
    if (sub >= 8) {
        // W2 transpose: R=4096, C=1024 -> 16 cx * 64 ry per expert; id in [0,8192)
        int id = grp * 8 + (sub - 8);
        float (*tl)[65] = (float(*)[65])shraw;
        int e = id >> 10, rem = id & 1023;
        int cx = rem & 15, ry = rem >> 4;
        tr_tile(W2 + (size_t)e * DIM * FDIM, w2t + (size_t)e * DIM * FDIM,
                FDIM, DIM, ry * 64, cx * 64, tl);
        return;
    }
    unsigned short* As = (unsigned short*)shraw;
    unsigned short* Bs = As + 3 * TILE;
    int pos = sub * 1024 + grp;                 // XCD = sub (b%8), sequential within XCD
    const int NTX = N_TOK / BM;                 // 32
    const int NTY = FDIM / BN;                  // 32
    int rt = pos % NTX;
    int tmp = pos / NTX;
    int n0 = (tmp % NTY) * BN;
    int e = tmp / NTY;
    int cnt = counts[e];
    if (rt * BM >= cnt) return;
    int off = offs[e];
    const unsigned short* Bp = w1t + (size_t)e * FDIM * DIM;

    GEMM_CORE(DIM, 32,
              (xbf + (size_t)(perm[off + ra] >> 1) * DIM),
              Bp)

    int rq = lane >> 4;
#pragma unroll
    for (int mf = 0; mf < 4; mf++) {
#pragma unroll
        for (int r = 0; r < 4; r++) {
            int row_local = wm * 64 + mf * 16 + rq * 4 + r;
            int grow = arow_base + row_local;
            if (grow < cnt) {
                unsigned short* hp = h + (size_t)(off + grow) * FDIM + n0 + wn * 64;
#pragma unroll
                for (int nf = 0; nf < 4; nf++)
                    hp[nf * 16 + rl] = f2bf(gelu_f(acc[mf][nf][r]));
            }
        }
    }
}

// GEMM2: ybuf = h @ w2t^T (K=4096 -> NT=128, N=1024); bf16 stores
__global__ __launch_bounds__(256) void gemm2_kernel(
    const unsigned short* __restrict__ h, const unsigned short* __restrict__ w2t,
    unsigned short* __restrict__ ybuf, const int* __restrict__ counts, const int* __restrict__ offs) {
    __shared__ unsigned short As[3 * TILE];
    __shared__ unsigned short Bs[3 * TILE];
    // grid: 32 rt x 8 nt x 8 e = 2048; XCD chunk (256) = one expert
    int L = blockIdx.x;
    int pos = (L & 7) * 256 + (L >> 3);
    int rt = pos & 31;
    int nt = (pos >> 5) & 7;
    int e = pos >> 8;
    int cnt = counts[e];
    if (rt * BM >= cnt) return;
    int off = offs[e];
    int n0 = nt * BN;
    const unsigned short* Bp = w2t + (size_t)e * DIM * FDIM;

    GEMM_CORE(FDIM, 128,
              (h + (size_t)(off + ra) * FDIM),
              Bp)

    int rq = lane >> 4;
#pragma unroll
    for (int mf = 0; mf < 4; mf++) {
#pragma unroll
        for (int r = 0; r < 4; r++) {
            int row_local = wm * 64 + mf * 16 + rq * 4 + r;
            int grow = arow_base + row_local;
            if (grow < cnt) {
                unsigned short* yp = ybuf + (size_t)(off + grow) * DIM + n0 + wn * 64;
#pragma unroll
                for (int nf = 0; nf < 4; nf++)
                    yp[nf * 16 + rl] = f2bf(acc[mf][nf][r]);
            }
        }
    }
}

// combine: out[n] = w0 * ybuf[inv[2n]] + w1 * ybuf[inv[2n+1]] (bf16 in, fp32 out);
// also writes aux_loss = 0
__global__ __launch_bounds__(256) void combine_kernel(
    const unsigned short* __restrict__ ybuf, const int* __restrict__ inv,
    const float* __restrict__ tk_w, float* __restrict__ out) {
    int n = blockIdx.x;
    int d = threadIdx.x * 4;
    int p0 = inv[2 * n], p1 = inv[2 * n + 1];
    float w0 = tk_w[2 * n], w1 = tk_w[2 * n + 1];
    ushort4 a = *(const ushort4*)(ybuf + (size_t)p0 * DIM + d);
    ushort4 b = *(const ushort4*)(ybuf + (size_t)p1 * DIM + d);
    float4 o = {w0 * bf2f(a.x) + w1 * bf2f(b.x),
                w0 * bf2f(a.y) + w1 * bf2f(b.y),
                w0 * bf2f(a.z) + w1 * bf2f(b.z),
                w0 * bf2f(a.w) + w1 * bf2f(b.w)};
    *(float4*)(out + (size_t)n * DIM + d) = o;
    if (n == 0 && threadIdx.x == 0) out[(size_t)N_TOK * DIM] = 0.f;  // aux_loss
}

extern "C" void kernel_launch(void* const* d_in, const int* in_sizes, int n_in,
                              void* d_out, int out_size, void* d_ws, size_t ws_size,
                              hipStream_t stream) {
    const float* x  = (const float*)d_in[0];
    const float* Wr = (const float*)d_in[1];
    const float* W1 = (const float*)d_in[2];
    const float* W2 = (const float*)d_in[3];
    float* out = (float*)d_out;

    char* w = (char*)d_ws;
    int*   counts = (int*)(w + 0);
    int*   offs   = (int*)(w + 64);
    int*   cursor = (int*)(w + 128);
    int*   tk_idx = (int*)(w + 256);
    float* tk_w   = (float*)(w + 256 + 32768);
    int*   perm   = (int*)(w + 256 + 65536);
    int*   inv    = (int*)(w + 256 + 131072);
    size_t base = (size_t)1 << 20;
    unsigned short* xbf  = (unsigned short*)(w + base);                       // 8 MB (bf16 x, token order)
    unsigned short* hbuf = (unsigned short*)(w + base + ((size_t)16 << 20));  // 64 MB
    unsigned short* w1t  = (unsigned short*)(w + base + ((size_t)80 << 20));  // 64 MB (dead after gemm1)
    unsigned short* w2t  = (unsigned short*)(w + base + ((size_t)144 << 20)); // 64 MB
    unsigned short* ybuf = (unsigned short*)(w + base + ((size_t)80 << 20));  // 16 MB, aliases w1t

    hipMemsetAsync(w, 0, 256, stream);

    // W1 transpose (2048 big tiles) + router (1024 blocks x 4 tokens), one launch
    tr1_router_kernel<<<3072, 256, 0, stream>>>(W1, w1t, x, Wr, xbf, tk_idx, tk_w, counts);
    scan_kernel<<<1, 64, 0, stream>>>(counts, offs, cursor);
    fill_kernel<<<N_TOK / 256, 256, 0, stream>>>(tk_idx, cursor, perm, inv);

    // gemm1 (8192 tiles, A permuted on the fly) + W2 transpose (8192 small tiles) fused
    gemm1_tr2_kernel<<<16384, 256, 0, stream>>>(xbf, w1t, hbuf, counts, offs, perm, W2, w2t);

    gemm2_kernel<<<32 * 8 * NEXP, 256, 0, stream>>>(hbuf, w2t, ybuf, counts, offs);
    combine_kernel<<<N_TOK, 256, 0, stream>>>(ybuf, inv, tk_w, out);
}

// Round 21
// 439.223 us; speedup vs baseline: 1.0857x; 1.0595x over previous
//
#include <hip/hip_runtime.h>
#include <hip/hip_bf16.h>

#define N_TOK 4096
#define DIM   1024
#define NEXP  8
#define FDIM  4096

#define BM 128
#define BN 128
#define BK 32
#define TILE (BM * BK)   // elems per LDS tile buffer (8 KB)

typedef __attribute__((ext_vector_type(8))) short bf16x8;
typedef __attribute__((ext_vector_type(4))) float f32x4;

__device__ __forceinline__ unsigned short f2bf(float f) {
    unsigned u = __builtin_bit_cast(unsigned, f);
    u = (u + 0x7fffu + ((u >> 16) & 1u)) >> 16;
    return (unsigned short)u;
}

__device__ __forceinline__ float bf2f(unsigned short u) {
    return __builtin_bit_cast(float, (unsigned)u << 16);
}

// exact-GELU via branch-free erf approx (A&S 7.1.26, |err_erf| < 1.5e-7 abs)
__device__ __forceinline__ float gelu_f(float v) {
    float x = v * 0.70710678118654752f;
    float ax = fabsf(x);
    float t = __builtin_amdgcn_rcpf(1.0f + 0.3275911f * ax);
    float poly = t * (0.254829592f + t * (-0.284496736f + t * (1.421413741f +
                 t * (-1.453152027f + t * 1.061405429f))));
    float e = __expf(-x * x);
    float er = copysignf(1.0f - poly * e, x);
    return 0.5f * v * (1.0f + er);
}

// async global->LDS, 16B per lane. LDS dest is wave-uniform base + lane*16.
__device__ __forceinline__ void gld16(const unsigned short* g, unsigned short* l) {
    __builtin_amdgcn_global_load_lds(
        (const __attribute__((address_space(1))) unsigned int*)g,
        (__attribute__((address_space(3))) unsigned int*)l, 16, 0, 0);
}

// small (64x64) transpose tile body: fp32 [R][C] -> bf16 [C][R]; tl = [64][65] f32
// (65 % 32 == 1 -> bank = c + r rotation, conflict-free scalar phases)
__device__ __forceinline__ void tr_tile(const float* in, unsigned short* out,
                                        int R, int C, int r0, int c0, float (*tl)[65]) {
    int t = threadIdx.x;
    int lr = t >> 4, lc = (t & 15) * 4;
#pragma unroll
    for (int it = 0; it < 4; it++) {
        int r = lr + it * 16;
        float4 v = *(const float4*)(in + (size_t)(r0 + r) * C + c0 + lc);
        tl[lc + 0][r] = v.x; tl[lc + 1][r] = v.y; tl[lc + 2][r] = v.z; tl[lc + 3][r] = v.w;
    }
    __syncthreads();
    int orow = t >> 3, orr = (t & 7) * 8;
#pragma unroll
    for (int it = 0; it < 2; it++) {
        int oc = orow + it * 32;
        unsigned short o[8];
#pragma unroll
        for (int j = 0; j < 8; j++) o[j] = f2bf(tl[oc][orr + j]);
        *(int4*)(out + (size_t)(c0 + oc) * R + r0 + orr) = *(const int4*)o;
    }
}

// 128x128 transpose tile body (fp32 [R][C] -> bf16 [C][R]); tl = [128][132] ushort
__device__ __forceinline__ void tr_tile128(const float* in, unsigned short* out,
                                           int R, int C, int r0, int c0,
                                           unsigned short (*tl)[132], int t) {
    int lr = t >> 5, lcq = (t & 31) * 4;
#pragma unroll
    for (int it = 0; it < 16; it++) {
        int r = lr + it * 8;
        float4 v = *(const float4*)(in + (size_t)(r0 + r) * C + c0 + lcq);
        unsigned short o[4] = {f2bf(v.x), f2bf(v.y), f2bf(v.z), f2bf(v.w)};
        *(uint2*)&tl[r][lcq] = *(const uint2*)o;
    }
    __syncthreads();
    int rchunk = (t & 15) * 8;
#pragma unroll
    for (int it = 0; it < 8; it++) {
        int oc = (t >> 4) + it * 16;
        unsigned short o[8];
#pragma unroll
        for (int j = 0; j < 8; j++) o[j] = tl[rchunk + j][oc];
        *(int4*)(out + (size_t)(c0 + oc) * R + r0 + rchunk) = *(const int4*)o;
    }
}

// heterogeneous: blocks [0,2048) = W1 transpose (128x128 tiles);
// blocks [2048,3072) = router (4 waves/block; also writes xbf = bf16 copy of x).
__global__ __launch_bounds__(256) void tr1_router_kernel(
    const float* __restrict__ W1, unsigned short* __restrict__ w1t,
    const float* __restrict__ x, const float* __restrict__ Wr,
    unsigned short* __restrict__ xbf,
    int* __restrict__ tk_idx, float* __restrict__ tk_w, int* __restrict__ counts) {
    __shared__ __align__(16) unsigned short tl[128][132];   // 33 KB
    int idx = blockIdx.x;
    int t = threadIdx.x;
    if (idx < 2048) {   // W1 [1024][4096] -> w1t [4096][1024]; 8 rt x 32 ct per expert
        int e = idx >> 8, rem = idx & 255;
        int ct = rem & 31, rt8 = rem >> 5;
        tr_tile128(W1 + (size_t)e * DIM * FDIM, w1t + (size_t)e * DIM * FDIM,
                   DIM, FDIM, rt8 * 128, ct * 128, tl, t);
        return;
    }
    // router: token n, one wave
    int n = (idx - 2048) * 4 + (t >> 6);
    int l = t & 63;
    float acc[8];
#pragma unroll
    for (int e = 0; e < 8; e++) acc[e] = 0.f;
    const float* xr = x + (size_t)n * DIM;
    unsigned short* xo = xbf + (size_t)n * DIM;
#pragma unroll 4
    for (int i = 0; i < 16; i++) {
        int d = i * 64 + l;
        float xv = xr[d];
        xo[d] = f2bf(xv);
        const float4* wr = (const float4*)(Wr + (size_t)d * 8);
        float4 w0 = wr[0], w1 = wr[1];
        acc[0] += xv * w0.x; acc[1] += xv * w0.y; acc[2] += xv * w0.z; acc[3] += xv * w0.w;
        acc[4] += xv * w1.x; acc[5] += xv * w1.y; acc[6] += xv * w1.z; acc[7] += xv * w1.w;
    }
#pragma unroll
    for (int off = 32; off >= 1; off >>= 1)
#pragma unroll
        for (int e = 0; e < 8; e++) acc[e] += __shfl_xor(acc[e], off);
    if (l == 0) {
        float mx = acc[0];
#pragma unroll
        for (int e = 1; e < 8; e++) mx = fmaxf(mx, acc[e]);
        float p[8], s = 0.f;
#pragma unroll
        for (int e = 0; e < 8; e++) { p[e] = expf(acc[e] - mx); s += p[e]; }
#pragma unroll
        for (int e = 0; e < 8; e++) p[e] /= s;
        int i0 = 0;
#pragma unroll
        for (int e = 1; e < 8; e++) if (p[e] > p[i0]) i0 = e;
        int i1 = (i0 == 0) ? 1 : 0;
#pragma unroll
        for (int e = 0; e < 8; e++) if (e != i0 && p[e] > p[i1]) i1 = e;
        float w0 = p[i0], w1 = p[i1], s2 = w0 + w1;
        w0 /= s2; w1 /= s2;
        tk_idx[2 * n] = i0; tk_idx[2 * n + 1] = i1;
        tk_w[2 * n] = w0;   tk_w[2 * n + 1] = w1;
        atomicAdd(&counts[i0], 1);
        atomicAdd(&counts[i1], 1);
    }
}

// merged scan + fill: single block, LDS-atomic cursors.
// thread 0 builds the prefix; then all 256 threads loop tokens assigning
// permutation slots via LDS atomics (order-invariant downstream).
__global__ __launch_bounds__(256) void scanfill_kernel(
    const int* __restrict__ counts, int* __restrict__ offs,
    const int* __restrict__ tk_idx, int* __restrict__ perm, int* __restrict__ inv) {
    __shared__ int cur[NEXP];
    int t = threadIdx.x;
    if (t == 0) {
        int a = 0;
        for (int e = 0; e < NEXP; e++) { offs[e] = a; cur[e] = a; a += counts[e]; }
        offs[NEXP] = a;
    }
    __syncthreads();
    for (int n = t; n < N_TOK; n += 256) {
        int i0 = tk_idx[2 * n], i1 = tk_idx[2 * n + 1];
        int p0 = atomicAdd(&cur[i0], 1);
        perm[p0] = 2 * n;
        inv[2 * n] = p0;
        int p1 = atomicAdd(&cur[i1], 1);
        perm[p1] = 2 * n + 1;
        inv[2 * n + 1] = p1;
    }
}

// ---------------- GEMM core (r5-exact, FROZEN): 3-buffer ring, 2-deep vmcnt(8), 2 barriers/iter ----------------
// Requires As/Bs (3*TILE ushorts each) in scope. 48 KB LDS -> 3 blocks/CU.
// Swizzle: phys 16B-block = logical_block ^ ((row>>1)&3); inverse on per-lane GLOBAL src, linear gld dest.
// AROW_PTR_: expression over `ra` yielding the A-row base pointer (enables permuted A).

#define GEMM_CORE(K_, NT_, AROW_PTR_, B_)                                               \
    int t = threadIdx.x;                                                                \
    int lane = t & 63, wid = t >> 6;                                                    \
    int wm = wid >> 1, wn = wid & 1;                                                    \
    int arow_base = rt * BM;                                                            \
    int srow = lane >> 2;                       /* row within 16-row segment */         \
    int logb = (lane & 3) ^ ((lane >> 3) & 3);  /* inverse-swizzled 16B block */        \
    const unsigned short* gA[2];                                                        \
    const unsigned short* gB[2];                                                        \
    _Pragma("unroll")                                                                   \
    for (int j = 0; j < 2; j++) {                                                       \
        int ra = min(arow_base + wid * 32 + j * 16 + srow, cnt - 1);                    \
        gA[j] = (AROW_PTR_) + logb * 8;                                                 \
        gB[j] = B_ + (size_t)(n0 + wid * 32 + j * 16 + srow) * K_ + logb * 8;           \
    }                                                                                   \
    f32x4 acc[4][4];                                                                    \
    _Pragma("unroll")                                                                   \
    for (int i = 0; i < 4; i++)                                                         \
        _Pragma("unroll")                                                               \
        for (int j = 0; j < 4; j++) acc[i][j] = (f32x4){0.f, 0.f, 0.f, 0.f};            \
    int rl = lane & 15;                                                                 \
    int kq = lane >> 4;                                                                 \
    int pb8 = (kq ^ ((rl >> 1) & 3)) * 8;       /* phys block offset for frag reads */  \
    auto stage = [&](int buf) {                                                         \
        unsigned short* la = As + buf * TILE + wid * 32 * BK;                           \
        unsigned short* lb = Bs + buf * TILE + wid * 32 * BK;                           \
        _Pragma("unroll")                                                               \
        for (int j = 0; j < 2; j++) { gld16(gA[j], la + j * 16 * BK); gA[j] += BK; }    \
        _Pragma("unroll")                                                               \
        for (int j = 0; j < 2; j++) { gld16(gB[j], lb + j * 16 * BK); gB[j] += BK; }    \
    };                                                                                  \
    auto compute = [&](int buf) {                                                       \
        const unsigned short* as = As + buf * TILE;                                     \
        const unsigned short* bs = Bs + buf * TILE;                                     \
        bf16x8 af[4], bfr[4];                                                           \
        _Pragma("unroll")                                                               \
        for (int mf = 0; mf < 4; mf++)                                                  \
            af[mf] = *(const bf16x8*)(as + (wm * 64 + mf * 16 + rl) * BK + pb8);        \
        _Pragma("unroll")                                                               \
        for (int nf = 0; nf < 4; nf++)                                                  \
            bfr[nf] = *(const bf16x8*)(bs + (wn * 64 + nf * 16 + rl) * BK + pb8);       \
        _Pragma("unroll")                                                               \
        for (int mf = 0; mf < 4; mf++)                                                  \
            _Pragma("unroll")                                                           \
            for (int nf = 0; nf < 4; nf++)                                              \
                acc[mf][nf] = __builtin_amdgcn_mfma_f32_16x16x32_bf16(                  \
                    af[mf], bfr[nf], acc[mf][nf], 0, 0, 0);                             \
    };                                                                                  \
    stage(0); stage(1);                                                                 \
    asm volatile("s_waitcnt vmcnt(4)" ::: "memory");  /* tile0 done, tile1 in flight */ \
    __builtin_amdgcn_s_barrier();                                                       \
    int cb = 0;                                                                         \
    for (int it = 0; it < NT_ - 2; ++it) {                                              \
        int sb = cb + 2; if (sb >= 3) sb -= 3;                                          \
        stage(sb);                                                                      \
        asm volatile("s_waitcnt vmcnt(8)" ::: "memory"); /* keep t+1,t+2 in flight */   \
        __builtin_amdgcn_s_barrier();                                                   \
        compute(cb);                                                                    \
        __builtin_amdgcn_s_barrier();                                                   \
        cb = cb + 1; if (cb >= 3) cb -= 3;                                              \
    }                                                                                   \
    asm volatile("s_waitcnt vmcnt(4)" ::: "memory");                                    \
    __builtin_amdgcn_s_barrier();                                                       \
    compute(cb);                                                                        \
    __builtin_amdgcn_s_barrier();                                                       \
    cb = cb + 1; if (cb >= 3) cb -= 3;                                                  \
    asm volatile("s_waitcnt vmcnt(0)" ::: "memory");                                    \
    __builtin_amdgcn_s_barrier();                                                       \
    compute(cb);

// heterogeneous: 16-block groups, sub 0-7 = gemm1 tiles (keeps b%8 XCD mapping),
// sub 8-15 = W2-transpose 64x64 tiles (conflict-free pattern).
// gemm1 A-rows staged DIRECTLY from xbf via perm (per-lane global addresses).
__global__ __launch_bounds__(256) void gemm1_tr2_kernel(
    const unsigned short* __restrict__ xbf, const unsigned short* __restrict__ w1t,
    unsigned short* __restrict__ h, const int* __restrict__ counts, const int* __restrict__ offs,
    const int* __restrict__ perm,
    const float* __restrict__ W2, unsigned short* __restrict__ w2t) {
    __shared__ __align__(16) char shraw[3 * TILE * 2 * sizeof(unsigned short)];  // 48 KB
    int Lx = blockIdx.x;
    int grp = Lx >> 4, sub = Lx & 15;
    if (sub >= 8) {
        // W2 transpose: R=4096, C=1024 -> 16 cx * 64 ry per expert; id in [0,8192)
        int id = grp * 8 + (sub - 8);
        float (*tl)[65] = (float(*)[65])shraw;
        int e = id >> 10, rem = id & 1023;
        int cx = rem & 15, ry = rem >> 4;
        tr_tile(W2 + (size_t)e * DIM * FDIM, w2t + (size_t)e * DIM * FDIM,
                FDIM, DIM, ry * 64, cx * 64, tl);
        return;
    }
    unsigned short* As = (unsigned short*)shraw;
    unsigned short* Bs = As + 3 * TILE;
    int pos = sub * 1024 + grp;                 // XCD = sub (b%8), sequential within XCD
    const int NTX = N_TOK / BM;                 // 32
    const int NTY = FDIM / BN;                  // 32
    int rt = pos % NTX;
    int tmp = pos / NTX;
    int n0 = (tmp % NTY) * BN;
    int e = tmp / NTY;
    int cnt = counts[e];
    if (rt * BM >= cnt) return;
    int off = offs[e];
    const unsigned short* Bp = w1t + (size_t)e * FDIM * DIM;

    GEMM_CORE(DIM, 32,
              (xbf + (size_t)(perm[off + ra] >> 1) * DIM),
              Bp)

    int rq = lane >> 4;
#pragma unroll
    for (int mf = 0; mf < 4; mf++) {
#pragma unroll
        for (int r = 0; r < 4; r++) {
            int row_local = wm * 64 + mf * 16 + rq * 4 + r;
            int grow = arow_base + row_local;
            if (grow < cnt) {
                unsigned short* hp = h + (size_t)(off + grow) * FDIM + n0 + wn * 64;
#pragma unroll
                for (int nf = 0; nf < 4; nf++)
                    hp[nf * 16 + rl] = f2bf(gelu_f(acc[mf][nf][r]));
            }
        }
    }
}

// GEMM2: ybuf = h @ w2t^T (K=4096 -> NT=128, N=1024); bf16 stores
__global__ __launch_bounds__(256) void gemm2_kernel(
    const unsigned short* __restrict__ h, const unsigned short* __restrict__ w2t,
    unsigned short* __restrict__ ybuf, const int* __restrict__ counts, const int* __restrict__ offs) {
    __shared__ unsigned short As[3 * TILE];
    __shared__ unsigned short Bs[3 * TILE];
    // grid: 32 rt x 8 nt x 8 e = 2048; XCD chunk (256) = one expert
    int L = blockIdx.x;
    int pos = (L & 7) * 256 + (L >> 3);
    int rt = pos & 31;
    int nt = (pos >> 5) & 7;
    int e = pos >> 8;
    int cnt = counts[e];
    if (rt * BM >= cnt) return;
    int off = offs[e];
    int n0 = nt * BN;
    const unsigned short* Bp = w2t + (size_t)e * DIM * FDIM;

    GEMM_CORE(FDIM, 128,
              (h + (size_t)(off + ra) * FDIM),
              Bp)

    int rq = lane >> 4;
#pragma unroll
    for (int mf = 0; mf < 4; mf++) {
#pragma unroll
        for (int r = 0; r < 4; r++) {
            int row_local = wm * 64 + mf * 16 + rq * 4 + r;
            int grow = arow_base + row_local;
            if (grow < cnt) {
                unsigned short* yp = ybuf + (size_t)(off + grow) * DIM + n0 + wn * 64;
#pragma unroll
                for (int nf = 0; nf < 4; nf++)
                    yp[nf * 16 + rl] = f2bf(acc[mf][nf][r]);
            }
        }
    }
}

// combine: out[n] = w0 * ybuf[inv[2n]] + w1 * ybuf[inv[2n+1]] (bf16 in, fp32 out);
// also writes aux_loss = 0
__global__ __launch_bounds__(256) void combine_kernel(
    const unsigned short* __restrict__ ybuf, const int* __restrict__ inv,
    const float* __restrict__ tk_w, float* __restrict__ out) {
    int n = blockIdx.x;
    int d = threadIdx.x * 4;
    int p0 = inv[2 * n], p1 = inv[2 * n + 1];
    float w0 = tk_w[2 * n], w1 = tk_w[2 * n + 1];
    ushort4 a = *(const ushort4*)(ybuf + (size_t)p0 * DIM + d);
    ushort4 b = *(const ushort4*)(ybuf + (size_t)p1 * DIM + d);
    float4 o = {w0 * bf2f(a.x) + w1 * bf2f(b.x),
                w0 * bf2f(a.y) + w1 * bf2f(b.y),
                w0 * bf2f(a.z) + w1 * bf2f(b.z),
                w0 * bf2f(a.w) + w1 * bf2f(b.w)};
    *(float4*)(out + (size_t)n * DIM + d) = o;
    if (n == 0 && threadIdx.x == 0) out[(size_t)N_TOK * DIM] = 0.f;  // aux_loss
}

extern "C" void kernel_launch(void* const* d_in, const int* in_sizes, int n_in,
                              void* d_out, int out_size, void* d_ws, size_t ws_size,
                              hipStream_t stream) {
    const float* x  = (const float*)d_in[0];
    const float* Wr = (const float*)d_in[1];
    const float* W1 = (const float*)d_in[2];
    const float* W2 = (const float*)d_in[3];
    float* out = (float*)d_out;

    char* w = (char*)d_ws;
    int*   counts = (int*)(w + 0);
    int*   offs   = (int*)(w + 64);
    int*   tk_idx = (int*)(w + 256);
    float* tk_w   = (float*)(w + 256 + 32768);
    int*   perm   = (int*)(w + 256 + 65536);
    int*   inv    = (int*)(w + 256 + 131072);
    size_t base = (size_t)1 << 20;
    unsigned short* xbf  = (unsigned short*)(w + base);                       // 8 MB (bf16 x, token order)
    unsigned short* hbuf = (unsigned short*)(w + base + ((size_t)16 << 20));  // 64 MB
    unsigned short* w1t  = (unsigned short*)(w + base + ((size_t)80 << 20));  // 64 MB (dead after gemm1)
    unsigned short* w2t  = (unsigned short*)(w + base + ((size_t)144 << 20)); // 64 MB
    unsigned short* ybuf = (unsigned short*)(w + base + ((size_t)80 << 20));  // 16 MB, aliases w1t

    hipMemsetAsync(w, 0, 256, stream);

    // W1 transpose (2048 big tiles) + router (1024 blocks x 4 tokens), one launch
    tr1_router_kernel<<<3072, 256, 0, stream>>>(W1, w1t, x, Wr, xbf, tk_idx, tk_w, counts);
    // merged scan + fill (single block, LDS-atomic cursors)
    scanfill_kernel<<<1, 256, 0, stream>>>(counts, offs, tk_idx, perm, inv);

    // gemm1 (8192 tiles, A permuted on the fly) + W2 transpose (8192 small tiles) fused
    gemm1_tr2_kernel<<<16384, 256, 0, stream>>>(xbf, w1t, hbuf, counts, offs, perm, W2, w2t);

    gemm2_kernel<<<32 * 8 * NEXP, 256, 0, stream>>>(hbuf, w2t, ybuf, counts, offs);
    combine_kernel<<<N_TOK, 256, 0, stream>>>(ybuf, inv, tk_w, out);
}

// Round 22
// 352.235 us; speedup vs baseline: 1.3538x; 1.2470x over previous
//
#include <hip/hip_runtime.h>
#include <hip/hip_bf16.h>

#define N_TOK 4096
#define DIM   1024
#define NEXP  8
#define FDIM  4096

#define BM 128
#define BN 128
#define BK 32
#define TILE (BM * BK)   // elems per LDS tile buffer (8 KB)

typedef __attribute__((ext_vector_type(8))) short bf16x8;
typedef __attribute__((ext_vector_type(4))) float f32x4;

__device__ __forceinline__ unsigned short f2bf(float f) {
    unsigned u = __builtin_bit_cast(unsigned, f);
    u = (u + 0x7fffu + ((u >> 16) & 1u)) >> 16;
    return (unsigned short)u;
}

__device__ __forceinline__ float bf2f(unsigned short u) {
    return __builtin_bit_cast(float, (unsigned)u << 16);
}

// exact-GELU via branch-free erf approx (A&S 7.1.26, |err_erf| < 1.5e-7 abs)
__device__ __forceinline__ float gelu_f(float v) {
    float x = v * 0.70710678118654752f;
    float ax = fabsf(x);
    float t = __builtin_amdgcn_rcpf(1.0f + 0.3275911f * ax);
    float poly = t * (0.254829592f + t * (-0.284496736f + t * (1.421413741f +
                 t * (-1.453152027f + t * 1.061405429f))));
    float e = __expf(-x * x);
    float er = copysignf(1.0f - poly * e, x);
    return 0.5f * v * (1.0f + er);
}

// async global->LDS, 16B per lane. LDS dest is wave-uniform base + lane*16.
__device__ __forceinline__ void gld16(const unsigned short* g, unsigned short* l) {
    __builtin_amdgcn_global_load_lds(
        (const __attribute__((address_space(1))) unsigned int*)g,
        (__attribute__((address_space(3))) unsigned int*)l, 16, 0, 0);
}

// small (64x64) transpose tile body: fp32 [R][C] -> bf16 [C][R]; tl = [64][65] f32
// (65 % 32 == 1 -> bank = c + r rotation, conflict-free scalar phases)
__device__ __forceinline__ void tr_tile(const float* in, unsigned short* out,
                                        int R, int C, int r0, int c0, float (*tl)[65]) {
    int t = threadIdx.x;
    int lr = t >> 4, lc = (t & 15) * 4;
#pragma unroll
    for (int it = 0; it < 4; it++) {
        int r = lr + it * 16;
        float4 v = *(const float4*)(in + (size_t)(r0 + r) * C + c0 + lc);
        tl[lc + 0][r] = v.x; tl[lc + 1][r] = v.y; tl[lc + 2][r] = v.z; tl[lc + 3][r] = v.w;
    }
    __syncthreads();
    int orow = t >> 3, orr = (t & 7) * 8;
#pragma unroll
    for (int it = 0; it < 2; it++) {
        int oc = orow + it * 32;
        unsigned short o[8];
#pragma unroll
        for (int j = 0; j < 8; j++) o[j] = f2bf(tl[oc][orr + j]);
        *(int4*)(out + (size_t)(c0 + oc) * R + r0 + orr) = *(const int4*)o;
    }
}

// 128x128 transpose tile body (fp32 [R][C] -> bf16 [C][R]); tl = [128][132] ushort
__device__ __forceinline__ void tr_tile128(const float* in, unsigned short* out,
                                           int R, int C, int r0, int c0,
                                           unsigned short (*tl)[132], int t) {
    int lr = t >> 5, lcq = (t & 31) * 4;
#pragma unroll
    for (int it = 0; it < 16; it++) {
        int r = lr + it * 8;
        float4 v = *(const float4*)(in + (size_t)(r0 + r) * C + c0 + lcq);
        unsigned short o[4] = {f2bf(v.x), f2bf(v.y), f2bf(v.z), f2bf(v.w)};
        *(uint2*)&tl[r][lcq] = *(const uint2*)o;
    }
    __syncthreads();
    int rchunk = (t & 15) * 8;
#pragma unroll
    for (int it = 0; it < 8; it++) {
        int oc = (t >> 4) + it * 16;
        unsigned short o[8];
#pragma unroll
        for (int j = 0; j < 8; j++) o[j] = tl[rchunk + j][oc];
        *(int4*)(out + (size_t)(c0 + oc) * R + r0 + rchunk) = *(const int4*)o;
    }
}

// heterogeneous: blocks [0,2048) = W1 transpose (128x128 tiles);
// blocks [2048,3072) = router (4 waves/block; also writes xbf = bf16 copy of x).
// NOTE: router no longer touches global counts (histogram moved to scanfill).
__global__ __launch_bounds__(256) void tr1_router_kernel(
    const float* __restrict__ W1, unsigned short* __restrict__ w1t,
    const float* __restrict__ x, const float* __restrict__ Wr,
    unsigned short* __restrict__ xbf,
    int* __restrict__ tk_idx, float* __restrict__ tk_w) {
    __shared__ __align__(16) unsigned short tl[128][132];   // 33 KB
    int idx = blockIdx.x;
    int t = threadIdx.x;
    if (idx < 2048) {   // W1 [1024][4096] -> w1t [4096][1024]; 8 rt x 32 ct per expert
        int e = idx >> 8, rem = idx & 255;
        int ct = rem & 31, rt8 = rem >> 5;
        tr_tile128(W1 + (size_t)e * DIM * FDIM, w1t + (size_t)e * DIM * FDIM,
                   DIM, FDIM, rt8 * 128, ct * 128, tl, t);
        return;
    }
    // router: token n, one wave
    int n = (idx - 2048) * 4 + (t >> 6);
    int l = t & 63;
    float acc[8];
#pragma unroll
    for (int e = 0; e < 8; e++) acc[e] = 0.f;
    const float* xr = x + (size_t)n * DIM;
    unsigned short* xo = xbf + (size_t)n * DIM;
#pragma unroll 4
    for (int i = 0; i < 16; i++) {
        int d = i * 64 + l;
        float xv = xr[d];
        xo[d] = f2bf(xv);
        const float4* wr = (const float4*)(Wr + (size_t)d * 8);
        float4 w0 = wr[0], w1 = wr[1];
        acc[0] += xv * w0.x; acc[1] += xv * w0.y; acc[2] += xv * w0.z; acc[3] += xv * w0.w;
        acc[4] += xv * w1.x; acc[5] += xv * w1.y; acc[6] += xv * w1.z; acc[7] += xv * w1.w;
    }
#pragma unroll
    for (int off = 32; off >= 1; off >>= 1)
#pragma unroll
        for (int e = 0; e < 8; e++) acc[e] += __shfl_xor(acc[e], off);
    if (l == 0) {
        float mx = acc[0];
#pragma unroll
        for (int e = 1; e < 8; e++) mx = fmaxf(mx, acc[e]);
        float p[8], s = 0.f;
#pragma unroll
        for (int e = 0; e < 8; e++) { p[e] = expf(acc[e] - mx); s += p[e]; }
#pragma unroll
        for (int e = 0; e < 8; e++) p[e] /= s;
        int i0 = 0;
#pragma unroll
        for (int e = 1; e < 8; e++) if (p[e] > p[i0]) i0 = e;
        int i1 = (i0 == 0) ? 1 : 0;
#pragma unroll
        for (int e = 0; e < 8; e++) if (e != i0 && p[e] > p[i1]) i1 = e;
        float w0 = p[i0], w1 = p[i1], s2 = w0 + w1;
        w0 /= s2; w1 /= s2;
        tk_idx[2 * n] = i0; tk_idx[2 * n + 1] = i1;
        tk_w[2 * n] = w0;   tk_w[2 * n + 1] = w1;
    }
}

// merged histogram + scan + fill: single block, LDS atomics only.
// Pass 1: LDS histogram of tk_idx. Thread 0: prefix -> offs[9] + counts[8].
// Pass 2: assign permutation slots via LDS cursors (order-invariant downstream).
// No global memset needed anywhere.
__global__ __launch_bounds__(256) void scanfill_kernel(
    int* __restrict__ counts, int* __restrict__ offs,
    const int* __restrict__ tk_idx, int* __restrict__ perm, int* __restrict__ inv) {
    __shared__ int hist[NEXP];
    __shared__ int cur[NEXP];
    int t = threadIdx.x;
    if (t < NEXP) hist[t] = 0;
    __syncthreads();
    for (int n = t; n < N_TOK; n += 256) {
        atomicAdd(&hist[tk_idx[2 * n]], 1);
        atomicAdd(&hist[tk_idx[2 * n + 1]], 1);
    }
    __syncthreads();
    if (t == 0) {
        int a = 0;
        for (int e = 0; e < NEXP; e++) {
            offs[e] = a; cur[e] = a; counts[e] = hist[e]; a += hist[e];
        }
        offs[NEXP] = a;
    }
    __syncthreads();
    for (int n = t; n < N_TOK; n += 256) {
        int i0 = tk_idx[2 * n], i1 = tk_idx[2 * n + 1];
        int p0 = atomicAdd(&cur[i0], 1);
        perm[p0] = 2 * n;
        inv[2 * n] = p0;
        int p1 = atomicAdd(&cur[i1], 1);
        perm[p1] = 2 * n + 1;
        inv[2 * n + 1] = p1;
    }
}

// ---------------- GEMM core (r5-exact, FROZEN): 3-buffer ring, 2-deep vmcnt(8), 2 barriers/iter ----------------
// Requires As/Bs (3*TILE ushorts each) in scope. 48 KB LDS -> 3 blocks/CU.
// Swizzle: phys 16B-block = logical_block ^ ((row>>1)&3); inverse on per-lane GLOBAL src, linear gld dest.
// AROW_PTR_: expression over `ra` yielding the A-row base pointer (enables permuted A).

#define GEMM_CORE(K_, NT_, AROW_PTR_, B_)                                               \
    int t = threadIdx.x;                                                                \
    int lane = t & 63, wid = t >> 6;                                                    \
    int wm = wid >> 1, wn = wid & 1;                                                    \
    int arow_base = rt * BM;                                                            \
    int srow = lane >> 2;                       /* row within 16-row segment */         \
    int logb = (lane & 3) ^ ((lane >> 3) & 3);  /* inverse-swizzled 16B block */        \
    const unsigned short* gA[2];                                                        \
    const unsigned short* gB[2];                                                        \
    _Pragma("unroll")                                                                   \
    for (int j = 0; j < 2; j++) {                                                       \
        int ra = min(arow_base + wid * 32 + j * 16 + srow, cnt - 1);                    \
        gA[j] = (AROW_PTR_) + logb * 8;                                                 \
        gB[j] = B_ + (size_t)(n0 + wid * 32 + j * 16 + srow) * K_ + logb * 8;           \
    }                                                                                   \
    f32x4 acc[4][4];                                                                    \
    _Pragma("unroll")                                                                   \
    for (int i = 0; i < 4; i++)                                                         \
        _Pragma("unroll")                                                               \
        for (int j = 0; j < 4; j++) acc[i][j] = (f32x4){0.f, 0.f, 0.f, 0.f};            \
    int rl = lane & 15;                                                                 \
    int kq = lane >> 4;                                                                 \
    int pb8 = (kq ^ ((rl >> 1) & 3)) * 8;       /* phys block offset for frag reads */  \
    auto stage = [&](int buf) {                                                         \
        unsigned short* la = As + buf * TILE + wid * 32 * BK;                           \
        unsigned short* lb = Bs + buf * TILE + wid * 32 * BK;                           \
        _Pragma("unroll")                                                               \
        for (int j = 0; j < 2; j++) { gld16(gA[j], la + j * 16 * BK); gA[j] += BK; }    \
        _Pragma("unroll")                                                               \
        for (int j = 0; j < 2; j++) { gld16(gB[j], lb + j * 16 * BK); gB[j] += BK; }    \
    };                                                                                  \
    auto compute = [&](int buf) {                                                       \
        const unsigned short* as = As + buf * TILE;                                     \
        const unsigned short* bs = Bs + buf * TILE;                                     \
        bf16x8 af[4], bfr[4];                                                           \
        _Pragma("unroll")                                                               \
        for (int mf = 0; mf < 4; mf++)                                                  \
            af[mf] = *(const bf16x8*)(as + (wm * 64 + mf * 16 + rl) * BK + pb8);        \
        _Pragma("unroll")                                                               \
        for (int nf = 0; nf < 4; nf++)                                                  \
            bfr[nf] = *(const bf16x8*)(bs + (wn * 64 + nf * 16 + rl) * BK + pb8);       \
        _Pragma("unroll")                                                               \
        for (int mf = 0; mf < 4; mf++)                                                  \
            _Pragma("unroll")                                                           \
            for (int nf = 0; nf < 4; nf++)                                              \
                acc[mf][nf] = __builtin_amdgcn_mfma_f32_16x16x32_bf16(                  \
                    af[mf], bfr[nf], acc[mf][nf], 0, 0, 0);                             \
    };                                                                                  \
    stage(0); stage(1);                                                                 \
    asm volatile("s_waitcnt vmcnt(4)" ::: "memory");  /* tile0 done, tile1 in flight */ \
    __builtin_amdgcn_s_barrier();                                                       \
    int cb = 0;                                                                         \
    for (int it = 0; it < NT_ - 2; ++it) {                                              \
        int sb = cb + 2; if (sb >= 3) sb -= 3;                                          \
        stage(sb);                                                                      \
        asm volatile("s_waitcnt vmcnt(8)" ::: "memory"); /* keep t+1,t+2 in flight */   \
        __builtin_amdgcn_s_barrier();                                                   \
        compute(cb);                                                                    \
        __builtin_amdgcn_s_barrier();                                                   \
        cb = cb + 1; if (cb >= 3) cb -= 3;                                              \
    }                                                                                   \
    asm volatile("s_waitcnt vmcnt(4)" ::: "memory");                                    \
    __builtin_amdgcn_s_barrier();                                                       \
    compute(cb);                                                                        \
    __builtin_amdgcn_s_barrier();                                                       \
    cb = cb + 1; if (cb >= 3) cb -= 3;                                                  \
    asm volatile("s_waitcnt vmcnt(0)" ::: "memory");                                    \
    __builtin_amdgcn_s_barrier();                                                       \
    compute(cb);

// heterogeneous: 16-block groups, sub 0-7 = gemm1 tiles (keeps b%8 XCD mapping),
// sub 8-15 = W2-transpose 64x64 tiles (conflict-free pattern).
// gemm1 A-rows staged DIRECTLY from xbf via perm (per-lane global addresses).
__global__ __launch_bounds__(256) void gemm1_tr2_kernel(
    const unsigned short* __restrict__ xbf, const unsigned short* __restrict__ w1t,
    unsigned short* __restrict__ h, const int* __restrict__ counts, const int* __restrict__ offs,
    const int* __restrict__ perm,
    const float* __restrict__ W2, unsigned short* __restrict__ w2t) {
    __shared__ __align__(16) char shraw[3 * TILE * 2 * sizeof(unsigned short)];  // 48 KB
    int Lx = blockIdx.x;
    int grp = Lx >> 4, sub = Lx & 15;
    if (sub >= 8) {
        // W2 transpose: R=4096, C=1024 -> 16 cx * 64 ry per expert; id in [0,8192)
        int id = grp * 8 + (sub - 8);
        float (*tl)[65] = (float(*)[65])shraw;
        int e = id >> 10, rem = id & 1023;
        int cx = rem & 15, ry = rem >> 4;
        tr_tile(W2 + (size_t)e * DIM * FDIM, w2t + (size_t)e * DIM * FDIM,
                FDIM, DIM, ry * 64, cx * 64, tl);
        return;
    }
    unsigned short* As = (unsigned short*)shraw;
    unsigned short* Bs = As + 3 * TILE;
    int pos = sub * 1024 + grp;                 // XCD = sub (b%8), sequential within XCD
    const int NTX = N_TOK / BM;                 // 32
    const int NTY = FDIM / BN;                  // 32
    int rt = pos % NTX;
    int tmp = pos / NTX;
    int n0 = (tmp % NTY) * BN;
    int e = tmp / NTY;
    int cnt = counts[e];
    if (rt * BM >= cnt) return;
    int off = offs[e];
    const unsigned short* Bp = w1t + (size_t)e * FDIM * DIM;

    GEMM_CORE(DIM, 32,
              (xbf + (size_t)(perm[off + ra] >> 1) * DIM),
              Bp)

    int rq = lane >> 4;
#pragma unroll
    for (int mf = 0; mf < 4; mf++) {
#pragma unroll
        for (int r = 0; r < 4; r++) {
            int row_local = wm * 64 + mf * 16 + rq * 4 + r;
            int grow = arow_base + row_local;
            if (grow < cnt) {
                unsigned short* hp = h + (size_t)(off + grow) * FDIM + n0 + wn * 64;
#pragma unroll
                for (int nf = 0; nf < 4; nf++)
                    hp[nf * 16 + rl] = f2bf(gelu_f(acc[mf][nf][r]));
            }
        }
    }
}

// GEMM2: ybuf = h @ w2t^T (K=4096 -> NT=128, N=1024); bf16 stores
__global__ __launch_bounds__(256) void gemm2_kernel(
    const unsigned short* __restrict__ h, const unsigned short* __restrict__ w2t,
    unsigned short* __restrict__ ybuf, const int* __restrict__ counts, const int* __restrict__ offs) {
    __shared__ unsigned short As[3 * TILE];
    __shared__ unsigned short Bs[3 * TILE];
    // grid: 32 rt x 8 nt x 8 e = 2048; XCD chunk (256) = one expert
    int L = blockIdx.x;
    int pos = (L & 7) * 256 + (L >> 3);
    int rt = pos & 31;
    int nt = (pos >> 5) & 7;
    int e = pos >> 8;
    int cnt = counts[e];
    if (rt * BM >= cnt) return;
    int off = offs[e];
    int n0 = nt * BN;
    const unsigned short* Bp = w2t + (size_t)e * DIM * FDIM;

    GEMM_CORE(FDIM, 128,
              (h + (size_t)(off + ra) * FDIM),
              Bp)

    int rq = lane >> 4;
#pragma unroll
    for (int mf = 0; mf < 4; mf++) {
#pragma unroll
        for (int r = 0; r < 4; r++) {
            int row_local = wm * 64 + mf * 16 + rq * 4 + r;
            int grow = arow_base + row_local;
            if (grow < cnt) {
                unsigned short* yp = ybuf + (size_t)(off + grow) * DIM + n0 + wn * 64;
#pragma unroll
                for (int nf = 0; nf < 4; nf++)
                    yp[nf * 16 + rl] = f2bf(acc[mf][nf][r]);
            }
        }
    }
}

// combine: out[n] = w0 * ybuf[inv[2n]] + w1 * ybuf[inv[2n+1]] (bf16 in, fp32 out);
// also writes aux_loss = 0
__global__ __launch_bounds__(256) void combine_kernel(
    const unsigned short* __restrict__ ybuf, const int* __restrict__ inv,
    const float* __restrict__ tk_w, float* __restrict__ out) {
    int n = blockIdx.x;
    int d = threadIdx.x * 4;
    int p0 = inv[2 * n], p1 = inv[2 * n + 1];
    float w0 = tk_w[2 * n], w1 = tk_w[2 * n + 1];
    ushort4 a = *(const ushort4*)(ybuf + (size_t)p0 * DIM + d);
    ushort4 b = *(const ushort4*)(ybuf + (size_t)p1 * DIM + d);
    float4 o = {w0 * bf2f(a.x) + w1 * bf2f(b.x),
                w0 * bf2f(a.y) + w1 * bf2f(b.y),
                w0 * bf2f(a.z) + w1 * bf2f(b.z),
                w0 * bf2f(a.w) + w1 * bf2f(b.w)};
    *(float4*)(out + (size_t)n * DIM + d) = o;
    if (n == 0 && threadIdx.x == 0) out[(size_t)N_TOK * DIM] = 0.f;  // aux_loss
}

extern "C" void kernel_launch(void* const* d_in, const int* in_sizes, int n_in,
                              void* d_out, int out_size, void* d_ws, size_t ws_size,
                              hipStream_t stream) {
    const float* x  = (const float*)d_in[0];
    const float* Wr = (const float*)d_in[1];
    const float* W1 = (const float*)d_in[2];
    const float* W2 = (const float*)d_in[3];
    float* out = (float*)d_out;

    char* w = (char*)d_ws;
    int*   counts = (int*)(w + 0);
    int*   offs   = (int*)(w + 64);
    int*   tk_idx = (int*)(w + 256);
    float* tk_w   = (float*)(w + 256 + 32768);
    int*   perm   = (int*)(w + 256 + 65536);
    int*   inv    = (int*)(w + 256 + 131072);
    size_t base = (size_t)1 << 20;
    unsigned short* xbf  = (unsigned short*)(w + base);                       // 8 MB (bf16 x, token order)
    unsigned short* hbuf = (unsigned short*)(w + base + ((size_t)16 << 20));  // 64 MB
    unsigned short* w1t  = (unsigned short*)(w + base + ((size_t)80 << 20));  // 64 MB (dead after gemm1)
    unsigned short* w2t  = (unsigned short*)(w + base + ((size_t)144 << 20)); // 64 MB
    unsigned short* ybuf = (unsigned short*)(w + base + ((size_t)80 << 20));  // 16 MB, aliases w1t

    // W1 transpose (2048 big tiles) + router (1024 blocks x 4 tokens), one launch.
    // No memset needed: counts/offs are produced wholesale by scanfill.
    tr1_router_kernel<<<3072, 256, 0, stream>>>(W1, w1t, x, Wr, xbf, tk_idx, tk_w);
    // merged histogram + scan + fill (single block, LDS atomics only)
    scanfill_kernel<<<1, 256, 0, stream>>>(counts, offs, tk_idx, perm, inv);

    // gemm1 (8192 tiles, A permuted on the fly) + W2 transpose (8192 small tiles) fused
    gemm1_tr2_kernel<<<16384, 256, 0, stream>>>(xbf, w1t, hbuf, counts, offs, perm, W2, w2t);

    gemm2_kernel<<<32 * 8 * NEXP, 256, 0, stream>>>(hbuf, w2t, ybuf, counts, offs);
    combine_kernel<<<N_TOK, 256, 0, stream>>>(ybuf, inv, tk_w, out);
}